// Round 1
// baseline (184.365 us; speedup 1.0000x reference)
//
#include <hip/hip_runtime.h>
#include <hip/hip_bf16.h>

#define SEQ    2048
#define NHEAD  16
#define HD     64
#define DMODEL 1024

using bf16 = __hip_bfloat16;
using short8 = __attribute__((ext_vector_type(8))) short;
using short4v = __attribute__((ext_vector_type(4))) short;
using f32x4  = __attribute__((ext_vector_type(4))) float;

__device__ __forceinline__ float fast_exp2(float x) {
  return __builtin_amdgcn_exp2f(x);   // v_exp_f32: D = 2^S0
}
// lgkmcnt(0) only; vmcnt=63, expcnt=7 untouched -> VMEM stays in flight
#define WAIT_LGKM0() __builtin_amdgcn_s_waitcnt(0xC07F)

__device__ __forceinline__ void gload_lds16(const bf16* g, bf16* l) {
  __builtin_amdgcn_global_load_lds(
      (const __attribute__((address_space(1))) void*)g,
      (__attribute__((address_space(3))) void*)l, 16, 0, 0);
}

// XOR bank swizzle for [16-row][32-elem] LDS tiles read as MFMA A/B operands
// [validated R11: conflicts 6.2M -> 1.77M]: LDS[row][chunk] holds
// global[row][chunk ^ ((row>>1)&3)] (chunk = 16B). Staging lane j sources
// global chunk (j&3)^((j>>3)&3); reads use chunk quad^((l16>>1)&3).

// ---------------- fused prep: convert x; transpose W_qkv, W_out -----------
__global__ void prep_k(const float* __restrict__ x, bf16* __restrict__ xb,
                       const float* __restrict__ Wqkv, bf16* __restrict__ WqkvT,
                       const float* __restrict__ Wout, bf16* __restrict__ WoutT) {
  __shared__ bf16 tile[32][33];
  const int id = blockIdx.x, tid = threadIdx.x;
  if (id < 2048) {                       // convert x: 2048 blocks x 2048 elems
    int i = (id * 256 + tid) * 8;
    bf16 tmp[8];
    #pragma unroll
    for (int j = 0; j < 8; ++j) tmp[j] = __float2bfloat16(x[i + j]);
    *(short8*)&xb[i] = *(short8*)tmp;
    return;
  }
  const float* in; bf16* out; int R, C, tx32, ty32;
  if (id < 2048 + 3072) {                // W_qkv [1024][3072] -> [3072][1024]
    int t = id - 2048; in = Wqkv; out = WqkvT; R = 1024; C = 3072;
    tx32 = t % 96; ty32 = t / 96;
  } else {                               // W_out [1024][1024] -> T
    int t = id - 5120; in = Wout; out = WoutT; R = 1024; C = 1024;
    tx32 = t % 32; ty32 = t / 32;
  }
  int c0 = tx32 * 32, r0 = ty32 * 32;
  int tx = tid & 31, ty = tid >> 5;
  #pragma unroll
  for (int i = ty; i < 32; i += 8)
    tile[i][tx] = __float2bfloat16(in[(size_t)(r0 + i) * C + c0 + tx]);
  __syncthreads();
  #pragma unroll
  for (int i = ty; i < 32; i += 8)
    out[(size_t)(c0 + i) * R + r0 + tx] = tile[tx][i];
}

// ---------------- MFMA GEMM: C[M,N] = A[M,K] * BT[N,K]^T + bias -----------
// m97-style global_load_lds(16B) staging + XOR bank swizzle.
// MODE 0: QKV (N=3072). Per-block uniform output target (128 | 1024):
//   n0 < 2048  (Q,K): SWAPPED orientation mfma(B,A) -> lane holds 4
//     n-contiguous values (c-contiguous in [b,h,l,c]) -> 8B vector stores.
//   n0 >= 2048 (V):   normal orientation -> lane holds 4 m-contiguous
//     values = l-contiguous in V^T [b,h,c,l] -> 8B vector stores, transpose
//     fused for free (transpose_v_k kernel deleted).
// MODE 1: out-proj (N=1024): fp32 store to outf
template <int MODE>
__global__ __launch_bounds__(256)
void gemm_bt(const bf16* __restrict__ A, const bf16* __restrict__ BT,
             const float* __restrict__ bias,
             bf16* __restrict__ out0, bf16* __restrict__ out1,
             bf16* __restrict__ out2, float* __restrict__ outf) {
  constexpr int K = 1024;
  __shared__ __align__(16) bf16 As[128 * 32];
  __shared__ __align__(16) bf16 Bs[128 * 32];
  const int tid = threadIdx.x;
  const int wave = tid >> 6, lane = tid & 63;
  const int quad = lane >> 4, l16 = lane & 15;
  const int waveM = (wave >> 1) * 64, waveN = (wave & 1) * 64;
  const int m0 = blockIdx.x * 128, n0 = blockIdx.y * 128;
  const bool swapped = (MODE == 0) && (n0 < 2048);   // Q,K blocks
  const int srow = (lane >> 2);                       // row within 16-row slab
  const int scol = (((lane & 3) ^ ((lane >> 3) & 3)) * 8);  // swizzled source
  const int q8   = (quad ^ ((l16 >> 1) & 3)) * 8;           // swizzled read

  const f32x4 zero4 = {0.f, 0.f, 0.f, 0.f};
  f32x4 acc[4][4];
  #pragma unroll
  for (int i = 0; i < 4; ++i)
    #pragma unroll
    for (int j = 0; j < 4; ++j) acc[i][j] = zero4;

  for (int k0 = 0; k0 < K; k0 += 32) {
    __syncthreads();   // prior frag reads done before LDS overwrite
    #pragma unroll
    for (int half = 0; half < 2; ++half) {
      int grow = half * 64 + wave * 16 + srow;
      gload_lds16(&A [(size_t)(m0 + grow) * K + k0 + scol],
                  &As[(half * 64 + wave * 16) * 32]);
      gload_lds16(&BT[(size_t)(n0 + grow) * K + k0 + scol],
                  &Bs[(half * 64 + wave * 16) * 32]);
    }
    __syncthreads();   // drains vmcnt(0): tile landed in LDS
    short8 af[4], bfm[4];
    #pragma unroll
    for (int mt = 0; mt < 4; ++mt)
      af[mt] = *(const short8*)&As[(waveM + mt * 16 + l16) * 32 + q8];
    #pragma unroll
    for (int nt = 0; nt < 4; ++nt)
      bfm[nt] = *(const short8*)&Bs[(waveN + nt * 16 + l16) * 32 + q8];
    if (swapped) {
      #pragma unroll
      for (int mt = 0; mt < 4; ++mt)
        #pragma unroll
        for (int nt = 0; nt < 4; ++nt)
          acc[mt][nt] = __builtin_amdgcn_mfma_f32_16x16x32_bf16(
              bfm[nt], af[mt], acc[mt][nt], 0, 0, 0);
    } else {
      #pragma unroll
      for (int mt = 0; mt < 4; ++mt)
        #pragma unroll
        for (int nt = 0; nt < 4; ++nt)
          acc[mt][nt] = __builtin_amdgcn_mfma_f32_16x16x32_bf16(
              af[mt], bfm[nt], acc[mt][nt], 0, 0, 0);
    }
  }

  // epilogue: C/D layout col=lane&15, row=quad*4+reg (verified mapping).
  // swapped => tile transposed: col=l16 -> m, row=quad*4+r -> n.
  if (MODE == 1) {
    #pragma unroll
    for (int nt = 0; nt < 4; ++nt) {
      int n = n0 + waveN + nt * 16 + l16;
      float bvv = bias[n];
      #pragma unroll
      for (int mt = 0; mt < 4; ++mt) {
        #pragma unroll
        for (int r = 0; r < 4; ++r) {
          int m = m0 + waveM + mt * 16 + quad * 4 + r;
          outf[(size_t)m * 1024 + n] = acc[mt][nt][r] + bvv;
        }
      }
    }
  } else if (swapped) {
    // Q or K: lane's 4 regs are n-contiguous -> contiguous c -> 8B stores
    #pragma unroll
    for (int nt = 0; nt < 4; ++nt) {
      int nb = n0 + waveN + nt * 16 + quad * 4;     // 4-aligned, 16B bias ld
      const f32x4 b4 = *(const f32x4*)&bias[nb];
      int oo = nb & 1023;
      int h = oo >> 6, cc = oo & 63;
      bf16* outp = (nb >> 10) ? out1 : out0;        // uniform per block
      #pragma unroll
      for (int mt = 0; mt < 4; ++mt) {
        int m = m0 + waveM + mt * 16 + l16;
        int bb = m >> 11, l = m & 2047;
        bf16 tmp[4];
        #pragma unroll
        for (int r = 0; r < 4; ++r)
          tmp[r] = __float2bfloat16(acc[mt][nt][r] + b4[r]);
        *(short4v*)&outp[((size_t)(bb * NHEAD + h) * SEQ + l) * HD + cc] =
            *(short4v*)tmp;
      }
    }
  } else {
    // V: lane's 4 regs are m-contiguous = l-contiguous in V^T [b,h,c,l]
    #pragma unroll
    for (int nt = 0; nt < 4; ++nt) {
      int n = n0 + waveN + nt * 16 + l16;           // 2048..3071
      float bvv = bias[n];
      int oo = n & 1023;
      int h = oo >> 6, cc = oo & 63;
      #pragma unroll
      for (int mt = 0; mt < 4; ++mt) {
        int m = m0 + waveM + mt * 16 + quad * 4;
        int bb = m >> 11, l = m & 2047;
        bf16 tmp[4];
        #pragma unroll
        for (int r = 0; r < 4; ++r)
          tmp[r] = __float2bfloat16(acc[mt][nt][r] + bvv);
        *(short4v*)&out2[((size_t)(bb * NHEAD + h) * HD + cc) * SEQ + l] =
            *(short4v*)tmp;
      }
    }
  }
}

// ---------------- flash attention v10: 1024 blocks, LPT, 3/CU -------------
// Block = 64 q-rows (4 waves x 16), ONE q-tile per block (pass loop gone).
// R12/R13 lessons kept: block-cooperative V, double-buffered K+V staging,
// XOR-swizzled LDS [R11], scale-free softmax (fixed m=8) [R8], XCD-local
// bh = id&31 [R10]. NEW: grid 1024 with qt = 31-(id>>5) (LPT: heaviest
// q-tiles dispatched first) + __launch_bounds__(256,3): LDS 41984B/block
// -> 3 blocks/CU = 12 waves/CU (was 2 blocks, 8 waves — grid-limited).
// s_setprio(1) around MFMA clusters (T5: +4-7% on independent-block attn).
__global__ __launch_bounds__(256, 3)
void attn_k(const bf16* __restrict__ Q, const bf16* __restrict__ Kb,
            const bf16* __restrict__ VT, bf16* __restrict__ O) {
  __shared__ __align__(16) bf16 Ks[2][2][64 * 32];  // [buf][d-half][k-row][32]
  __shared__ __align__(16) bf16 Vs[2][2][64 * 32];  // [buf][k-chunk][d-row][32]
  __shared__ __align__(16) bf16 Plds[4][16][72];    // per-wave P / O staging
  const int tid = threadIdx.x;
  const int wave = tid >> 6, lane = tid & 63;
  const int quad = lane >> 4, l16 = lane & 15;
  const int srow = lane >> 2;
  const int scol = (((lane & 3) ^ ((lane >> 3) & 3)) * 8);  // swizzled source
  const int q8   = (quad ^ ((l16 >> 1) & 3)) * 8;           // swizzled read
  const int id = blockIdx.x;
  const int bh = id & 31;                  // XCD-local: same bh -> same XCD
  const int qt = 31 - (id >> 5);           // LPT: big blocks first
  const int b = bh >> 4, h = bh & 15;

  const bf16* Qp = Q  + (size_t)bh * SEQ * HD;
  const bf16* Kp = Kb + (size_t)bh * SEQ * HD;
  const bf16* Vp = VT + (size_t)bh * HD * SEQ;

  const f32x4 zero4 = {0.f, 0.f, 0.f, 0.f};
  const float c = 0.18033688011112042f;        // 0.125 * log2(e)
  const float mc = 8.0f * c;                   // fixed stabilizer * c

  const int q0w = qt * 64 + wave * 16;         // wave's 16 q rows
  const int q_lane = q0w + l16;
  const int ntiles = qt + 1;                   // K-tiles of 64

  // Q as B-operand: B[n=l16 (q)][k=quad*8+j (d)]
  short8 qf0 = *(const short8*)&Qp[(size_t)(q0w + l16) * HD + quad * 8];
  short8 qf1 = *(const short8*)&Qp[(size_t)(q0w + l16) * HD + 32 + quad * 8];

  f32x4 oacc[4];                     // O^T: col=l16=q, row=quad*4+r (d)
  #pragma unroll
  for (int dt = 0; dt < 4; ++dt) oacc[dt] = zero4;
  float l4[4] = {0.f, 0.f, 0.f, 0.f};

  // prologue: stage tile 0 into buf 0
  {
    const int k0 = 0;
    #pragma unroll
    for (int hh = 0; hh < 2; ++hh)
      gload_lds16(&Kp[(size_t)(k0 + wave * 16 + srow) * HD + hh * 32 + scol],
                  &Ks[0][hh][(wave * 16) * 32]);
    #pragma unroll
    for (int ch = 0; ch < 2; ++ch)
      gload_lds16(&Vp[(size_t)(wave * 16 + srow) * SEQ + k0 + ch * 32 + scol],
                  &Vs[0][ch][(wave * 16) * 32]);
  }
  __syncthreads();   // buf0 staged (vmcnt drained by barrier)

  for (int t = 0; t < ntiles; ++t) {
    const int buf = t & 1;
    // ---- prefetch tile t+1 into the other buffer (no barrier) ----
    if (t + 1 < ntiles) {
      const int k1 = (t + 1) << 6, nb = buf ^ 1;
      #pragma unroll
      for (int hh = 0; hh < 2; ++hh)
        gload_lds16(&Kp[(size_t)(k1 + wave * 16 + srow) * HD + hh * 32 + scol],
                    &Ks[nb][hh][(wave * 16) * 32]);
      #pragma unroll
      for (int ch = 0; ch < 2; ++ch)
        gload_lds16(&Vp[(size_t)(wave * 16 + srow) * SEQ + k1 + ch * 32 + scol],
                    &Vs[nb][ch][(wave * 16) * 32]);
    }
    const int k0 = t << 6;

    // ---- S^T: 4 groups of 16 k-rows, swizzled LDS reads ----
    f32x4 s[4];
    __builtin_amdgcn_s_setprio(1);
    #pragma unroll
    for (int g = 0; g < 4; ++g) {
      short8 ka = *(const short8*)&Ks[buf][0][(g * 16 + l16) * 32 + q8];
      short8 kb = *(const short8*)&Ks[buf][1][(g * 16 + l16) * 32 + q8];
      f32x4 sg = zero4;
      sg = __builtin_amdgcn_mfma_f32_16x16x32_bf16(ka, qf0, sg, 0, 0, 0);
      sg = __builtin_amdgcn_mfma_f32_16x16x32_bf16(kb, qf1, sg, 0, 0, 0);
      s[g] = sg;
    }
    __builtin_amdgcn_s_setprio(0);

    // ---- causal mask (diagonal tile only: t == qt) ----
    if (t == ntiles - 1) {
      #pragma unroll
      for (int g = 0; g < 4; ++g)
        #pragma unroll
        for (int r = 0; r < 4; ++r) {
          int k = k0 + g * 16 + quad * 4 + r;
          s[g][r] = (k <= q_lane) ? s[g][r] : -__builtin_inff();
        }
    }

    // ---- p = exp2(s*c - mc); per-lane denom; stage P^T per-wave ----
    #pragma unroll
    for (int g = 0; g < 4; ++g) {
      bf16 pb[4];
      #pragma unroll
      for (int r = 0; r < 4; ++r) {
        float p = fast_exp2(__builtin_fmaf(s[g][r], c, -mc)); // masked -> 0
        l4[r] += p;
        pb[r] = __float2bfloat16(p);
      }
      *(short4v*)&Plds[wave][l16][g * 16 + quad * 4] = *(short4v*)pb;
    }
    WAIT_LGKM0();   // drain own-wave LDS writes (per-wave slab)

    // ---- PV: O^T += V^T(A) . P^T(B), swizzled V reads ----
    __builtin_amdgcn_s_setprio(1);
    #pragma unroll
    for (int ch = 0; ch < 2; ++ch) {
      short8 pf = *(const short8*)&Plds[wave][l16][ch * 32 + quad * 8];
      #pragma unroll
      for (int dt = 0; dt < 4; ++dt) {
        short8 vf = *(const short8*)&Vs[buf][ch][(dt * 16 + l16) * 32 + q8];
        oacc[dt] = __builtin_amdgcn_mfma_f32_16x16x32_bf16(vf, pf, oacc[dt], 0, 0, 0);
      }
    }
    __builtin_amdgcn_s_setprio(0);
    // barrier: everyone done reading buf t; staging of t+1 drained
    __syncthreads();
  }

  // ---- fold denom once: 4 reg adds + 2 shuffles ----
  float l_i = (l4[0] + l4[1]) + (l4[2] + l4[3]);
  l_i += __shfl_xor(l_i, 16, 64);
  l_i += __shfl_xor(l_i, 32, 64);
  float inv = 1.f / l_i;

  // ---- epilogue: O^T -> token-major O via per-wave LDS transpose ----
  #pragma unroll
  for (int dt = 0; dt < 4; ++dt) {
    bf16 ob[4];
    #pragma unroll
    for (int r = 0; r < 4; ++r) ob[r] = __float2bfloat16(oacc[dt][r] * inv);
    *(short4v*)&Plds[wave][l16][dt * 16 + quad * 4] = *(short4v*)ob;
  }
  WAIT_LGKM0();
  {
    int row = lane >> 2;                 // 0..15 (q within wave strip)
    int col = (lane & 3) * 16;           // 0,16,32,48 (d)
    short8 o0 = *(const short8*)&Plds[wave][row][col];
    short8 o1 = *(const short8*)&Plds[wave][row][col + 8];
    size_t base = ((size_t)(b * SEQ + q0w + row)) * DMODEL + h * HD + col;
    *(short8*)&O[base]     = o0;
    *(short8*)&O[base + 8] = o1;
  }
}

// --------------------------------------------------------------------------
extern "C" void kernel_launch(void* const* d_in, const int* in_sizes, int n_in,
                              void* d_out, int out_size, void* d_ws, size_t ws_size,
                              hipStream_t stream) {
  const float* x    = (const float*)d_in[0];
  const float* Wqkv = (const float*)d_in[1];
  const float* bqkv = (const float*)d_in[2];
  const float* Wout = (const float*)d_in[3];
  const float* bout = (const float*)d_in[4];
  float* out = (float*)d_out;   // fp32 output (16 MB)

  // Workspace (32 MB + 16 KB):
  //   [16K, +8M)   Kbuf  [b,h,l,c]
  //   [+8M, +16M)  VTb   [b,h,c,l]  (written directly by gemm<0> now)
  //   [+16M,+24M)  xb (dead after gemm<0>), AO overlays it
  //   [+24M,+30M)  WqkvT
  //   [+30M,+32M)  WoutT
  // d_out doubles as staging: [0,8M) Qb (bf16); dead before the final fp32
  // GEMM overwrites d_out.
  char* ws = (char*)d_ws;
  const size_t MB = 1024 * 1024;
  char* big    = ws + 16384;
  bf16* Kbuf   = (bf16*)(big);
  bf16* VTb    = (bf16*)(big + 8 * MB);
  bf16* xb     = (bf16*)(big + 16 * MB);
  bf16* AO     = (bf16*)(big + 16 * MB);
  bf16* WqkvT  = (bf16*)(big + 24 * MB);
  bf16* WoutT  = (bf16*)(big + 30 * MB);
  bf16* Qb     = (bf16*)d_out;

  // 1) fused prep: convert x + transpose both weight matrices (1 dispatch)
  prep_k<<<6144, 256, 0, stream>>>(x, xb, Wqkv, WqkvT, Wout, WoutT);
  // 2) QKV GEMM; Q,K scattered coalesced [b,h,l,c]; V written as [b,h,c,l]
  gemm_bt<0><<<dim3(4096 / 128, 3072 / 128), 256, 0, stream>>>(
      xb, WqkvT, bqkv, Qb, Kbuf, VTb, nullptr);
  // 3) flash attention (1024 blocks = 3/CU, LPT order, XCD-local bh)
  attn_k<<<1024, 256, 0, stream>>>(Qb, Kbuf, VTb, AO);
  // 4) output projection -> fp32 d_out
  gemm_bt<1><<<dim3(4096 / 128, 1024 / 128), 256, 0, stream>>>(
      AO, WoutT, bout, nullptr, nullptr, nullptr, out);
}